// Round 12
// baseline (162.422 us; speedup 1.0000x reference)
//
#include <hip/hip_runtime.h>
#include <cstdint>
#include <cstddef>
#include <math.h>

// CompactCausalAttention: B=4, T=2048, D_IN=D_OUT=1024, fp32 in/out.
// bf16 MFMA, 256^2 core. Round 12: ONE phase per K-tile (1 barrier + 1 vmcnt
// per K-tile, was 2+2). Counted lgkmcnt threads h1 reads under h0 MFMA with
// zero extra registers; staging same-phase-sealed (issued early, W0 late).
//   ws layout (70MB):
//     Xb  bf16 [8192][1024]          @ 0        (16MB)
//     Wt  bf16 [3][1024][1024] (W^T) @ 16777216 (6MB)
//     Q   bf16 [8192][1024]          @ 23068672 (16MB)
//     K   bf16 [8192][1024]          @ 39845888 (16MB)
//     Vt  bf16 [4][1024][2048] (V^T) @ 56623104 (16MB)
//     S   bf16 [4][36][256][256] packed lower-tri @ 0 (18MB; after k_v)
//     PVpartial fp32 [112][256][256] @ 23068672 (dead Q/K)
// order: cvt -> qk -> v -> sg -> softmax -> pv -> fix

typedef __attribute__((ext_vector_type(4))) float f32x4;
typedef __attribute__((ext_vector_type(8))) short s16x8;

#define AS1(p) ((const __attribute__((address_space(1))) void*)(p))
#define AS3(p) ((__attribute__((address_space(3))) void*)(p))
#define BARRIER() asm volatile("s_barrier" ::: "memory")
#define W0c asm volatile("s_waitcnt vmcnt(0)" ::: "memory")
#define LGKM(n) do { asm volatile("s_waitcnt lgkmcnt(" #n ")" ::: "memory"); \
                     __builtin_amdgcn_sched_barrier(0); } while (0)

static __device__ __forceinline__ unsigned short f2bf(float x) {
  unsigned int u = __float_as_uint(x);
  unsigned int r = u + 0x7FFFu + ((u >> 16) & 1u);   // RNE
  return (unsigned short)(r >> 16);
}
static __device__ __forceinline__ float bf2f(unsigned short h) {
  return __uint_as_float(((unsigned int)h) << 16);
}

// ---------- merged convert: X (blocks 0..4095) + W transpose (4096..4863) ----------
__global__ __launch_bounds__(256) void k_cvt(const float* __restrict__ X,
                                             const float* __restrict__ W0p,
                                             const float* __restrict__ W1p,
                                             const float* __restrict__ W2p,
                                             unsigned short* __restrict__ Xb,
                                             unsigned short* __restrict__ Wt) {
  __shared__ float tile[64][65];
  const int bx = blockIdx.x;
  if (bx < 4096) {
    size_t i = ((size_t)bx * 256 + threadIdx.x) * 8;
    float4 a = *(const float4*)(X + i);
    float4 b = *(const float4*)(X + i + 4);
    union { unsigned short us[8]; uint4 v; } o;
    o.us[0] = f2bf(a.x); o.us[1] = f2bf(a.y); o.us[2] = f2bf(a.z); o.us[3] = f2bf(a.w);
    o.us[4] = f2bf(b.x); o.us[5] = f2bf(b.y); o.us[6] = f2bf(b.z); o.us[7] = f2bf(b.w);
    *(uint4*)(Xb + i) = o.v;
    return;
  }
  const int bx2 = bx - 4096;
  const int z = bx2 >> 8, t = bx2 & 255;
  const float* W = z == 0 ? W0p : (z == 1 ? W1p : W2p);
  unsigned short* dst = Wt + (size_t)z * 1048576;
  const int k0 = (t >> 4) * 64, n0 = (t & 15) * 64;
  const int tr = threadIdx.x >> 4, tc = (threadIdx.x & 15) * 4;
  for (int i = 0; i < 4; ++i) {
    int r = tr + i * 16;
    float4 v = *(const float4*)(W + (size_t)(k0 + r) * 1024 + n0 + tc);
    tile[r][tc + 0] = v.x; tile[r][tc + 1] = v.y;
    tile[r][tc + 2] = v.z; tile[r][tc + 3] = v.w;
  }
  __syncthreads();
  for (int i = 0; i < 4; ++i) {
    int r = tr + i * 16;  // n-local
    ushort4 o;
    o.x = f2bf(tile[tc + 0][r]); o.y = f2bf(tile[tc + 1][r]);
    o.z = f2bf(tile[tc + 2][r]); o.w = f2bf(tile[tc + 3][r]);
    *(ushort4*)(dst + (size_t)(n0 + r) * 1024 + k0 + tc) = o;
  }
}

// ====================== 256^2 core, 1 phase / K-tile ======================
// 512 thr = 8 waves (2M x 4N), per-wave output 128x64, BK=64 (2 k-halves).
// LDS: A k-half regions [256][32]bf16 @ ((t&1)*2+h)*16384; B same @ +65536.
// Swizzle: 16B slot ^= (row>>1)&3; sources pre-swizzled (linear gload_lds dst).
static __device__ __forceinline__ void stage2(const char* src, size_t ld128, char* dst) {
  __builtin_amdgcn_global_load_lds(AS1(src), AS3(dst), 16, 0, 0);
  __builtin_amdgcn_global_load_lds(AS1(src + ld128), AS3(dst + 8192), 16, 0, 0);
}

template <class FA, class FB>
static __device__ __forceinline__ void core256(const char* __restrict__ As,
                                               const char* __restrict__ Bs,
                                               size_t ldA128, size_t ldB128,
                                               FA offA, FB offB,
                                               int nkt, char* smem, f32x4 (&acc)[8][4]) {
  const int tid = threadIdx.x, w = tid >> 6, lane = tid & 63;
  const int lr = lane & 15, lq = lane >> 4;
  const int wm = (w >> 2) * 128, wn = (w & 3) * 64;
  char* ldsA = smem + w * 1024;
  char* ldsB = smem + 65536 + w * 1024;
  s16x8 afA[4], afB[4], bfr[4];

#define STG_A(t, h) stage2(As + offA((t), (h)), ldA128, ldsA + (((t) & 1) * 2 + (h)) * 16384)
#define STG_B(t, h) stage2(Bs + offB((t), (h)), ldB128, ldsB + (((t) & 1) * 2 + (h)) * 16384)
#define STG(t, h) do { STG_A(t, h); STG_B(t, h); } while (0)
#define RD_A(buf, h, r) (*(const s16x8*)(smem + ((buf) * 2 + (h)) * 16384 + (r) * 64 + ((lq ^ (((r) >> 1) & 3)) << 4)))
#define RD_B(buf, h, r) (*(const s16x8*)(smem + 65536 + ((buf) * 2 + (h)) * 16384 + (r) * 64 + ((lq ^ (((r) >> 1) & 3)) << 4)))
#define MMQ(AF, BF, base) \
  _Pragma("unroll") for (int i = 0; i < 4; ++i) \
  _Pragma("unroll") for (int c = 0; c < 4; ++c) \
    acc[(base) + i][c] = __builtin_amdgcn_mfma_f32_16x16x32_bf16(AF[i], BF[c], acc[(base) + i][c], 0, 0, 0)

  // prologue: stage tile 0 (both k-halves, 8 loads); drain; barrier
  STG(0, 0); STG(0, 1);
  W0c; BARRIER();

  for (int t = 0; t < nkt; ++t) {
    const int _bf = t & 1;
    const bool more = (t + 1) < nkt;
    // --- h0 reads: G1=afA(4), G2=bfr(4), G3=afB(4) ---
#pragma unroll
    for (int i = 0; i < 4; ++i) afA[i] = RD_A(_bf, 0, wm + i * 16 + lr);
#pragma unroll
    for (int c = 0; c < 4; ++c) bfr[c] = RD_B(_bf, 0, wn + c * 16 + lr);
#pragma unroll
    for (int i = 0; i < 4; ++i) afB[i] = RD_A(_bf, 0, wm + 64 + i * 16 + lr);
    // stage t+1 early: full phase to complete before W0c at the end
    if (more) { STG(t + 1, 0); STG(t + 1, 1); }
    LGKM(4);                                    // G1+G2 done
    __builtin_amdgcn_s_setprio(1);
    MMQ(afA, bfr, 0);                           // h0-lo
    LGKM(0);                                    // G3 done
    __builtin_amdgcn_s_setprio(0);
    // --- G4 = afA <- h1 A-lo; drains under h0-hi MFMA ---
#pragma unroll
    for (int i = 0; i < 4; ++i) afA[i] = RD_A(_bf, 1, wm + i * 16 + lr);
    __builtin_amdgcn_s_setprio(1);
    MMQ(afB, bfr, 4);                           // h0-hi (afB,bfr still h0)
    __builtin_amdgcn_s_setprio(0);
    // --- G5 = bfr <- h1 B; G6 = afB <- h1 A-hi ---
#pragma unroll
    for (int c = 0; c < 4; ++c) bfr[c] = RD_B(_bf, 1, wn + c * 16 + lr);
#pragma unroll
    for (int i = 0; i < 4; ++i) afB[i] = RD_A(_bf, 1, wm + 64 + i * 16 + lr);
    LGKM(4);                                    // G4+G5 done (G6 pending)
    __builtin_amdgcn_s_setprio(1);
    MMQ(afA, bfr, 0);                           // h1-lo
    LGKM(0);                                    // G6 done
    MMQ(afB, bfr, 4);                           // h1-hi
    __builtin_amdgcn_s_setprio(0);
    if (more) { W0c; }                          // seal tile t+1 staging
    BARRIER();
  }

#undef STG_A
#undef STG_B
#undef STG
#undef RD_A
#undef RD_B
#undef MMQ
}

// ====================== 128x256 core (k_v), 1 phase / K-tile ======================
// 8 waves, wave tile 64x64. LDS 96KB: A [2][2][128][32] @0, B [2][2][256][32] @32768.
template <class FA, class FB>
static __device__ __forceinline__ void core_v(const char* __restrict__ As,
                                              const char* __restrict__ Bs,
                                              size_t ldA128, size_t ldB128,
                                              FA offA, FB offB,
                                              int nkt, char* smem, f32x4 (&acc)[4][4]) {
  const int tid = threadIdx.x, w = tid >> 6, lane = tid & 63;
  const int lr = lane & 15, lq = lane >> 4;
  const int wm = (w >> 2) * 64, wn = (w & 3) * 64;
  char* ldsA = smem + w * 1024;
  char* ldsB = smem + 32768 + w * 1024;
  s16x8 af[4], bfr[4];

#define STG_A(t, h) __builtin_amdgcn_global_load_lds(AS1(As + offA((t), (h))), \
    AS3(ldsA + (((t) & 1) * 2 + (h)) * 8192), 16, 0, 0)
#define STG_B(t, h) stage2(Bs + offB((t), (h)), ldB128, ldsB + (((t) & 1) * 2 + (h)) * 16384)
#define STG(t, h) do { STG_A(t, h); STG_B(t, h); } while (0)
#define RD_A(buf, h, r) (*(const s16x8*)(smem + ((buf) * 2 + (h)) * 8192 + (r) * 64 + ((lq ^ (((r) >> 1) & 3)) << 4)))
#define RD_B(buf, h, r) (*(const s16x8*)(smem + 32768 + ((buf) * 2 + (h)) * 16384 + (r) * 64 + ((lq ^ (((r) >> 1) & 3)) << 4)))
#define MMV(AF, BF) \
  _Pragma("unroll") for (int i = 0; i < 4; ++i) \
  _Pragma("unroll") for (int c = 0; c < 4; ++c) \
    acc[i][c] = __builtin_amdgcn_mfma_f32_16x16x32_bf16(AF[i], BF[c], acc[i][c], 0, 0, 0)

  STG(0, 0); STG(0, 1);
  W0c; BARRIER();

  for (int t = 0; t < nkt; ++t) {
    const int _bf = t & 1;
    const bool more = (t + 1) < nkt;
#pragma unroll
    for (int i = 0; i < 4; ++i) af[i] = RD_A(_bf, 0, wm + i * 16 + lr);
#pragma unroll
    for (int c = 0; c < 4; ++c) bfr[c] = RD_B(_bf, 0, wn + c * 16 + lr);
    if (more) { STG(t + 1, 0); STG(t + 1, 1); }
    LGKM(0);
    __builtin_amdgcn_s_setprio(1);
    MMV(af, bfr);
    __builtin_amdgcn_s_setprio(0);
#pragma unroll
    for (int i = 0; i < 4; ++i) af[i] = RD_A(_bf, 1, wm + i * 16 + lr);
#pragma unroll
    for (int c = 0; c < 4; ++c) bfr[c] = RD_B(_bf, 1, wn + c * 16 + lr);
    LGKM(0);
    __builtin_amdgcn_s_setprio(1);
    MMV(af, bfr);
    __builtin_amdgcn_s_setprio(0);
    if (more) { W0c; }
    BARRIER();
  }

#undef STG_A
#undef STG_B
#undef STG
#undef RD_A
#undef RD_B
#undef MMV
}

struct OffLinear {
  __device__ __forceinline__ size_t operator()(int t, int h) const {
    return (size_t)t * 128 + (size_t)h * 64;
  }
};
struct OffTriK {   // packed S tiles with k-chunk offset (BK64 units)
  int k0;
  __device__ __forceinline__ size_t operator()(int t, int h) const {
    int g = k0 + t;
    return (size_t)(g >> 2) * 131072 + (size_t)(g & 3) * 128 + (size_t)h * 64;
  }
};
struct OffLinK {   // linear with k-chunk offset
  int k0;
  __device__ __forceinline__ size_t operator()(int t, int h) const {
    return (size_t)(k0 + t) * 128 + (size_t)h * 64;
  }
};

static __device__ __forceinline__ void lane_src(int& rowl, int& slot) {
  const int tid = threadIdx.x, w = tid >> 6, lane = tid & 63;
  rowl = w * 16 + (lane >> 2);
  slot = (lane & 3) ^ ((rowl >> 1) & 3);
}

// ---------- Q,K projection: 256 blocks ----------
__global__ __launch_bounds__(512, 2) void k_qk(const unsigned short* __restrict__ Xb,
                                               const unsigned short* __restrict__ Wt,
                                               unsigned short* __restrict__ Qm,
                                               unsigned short* __restrict__ Km) {
  __shared__ char smem[131072];
  const int by = blockIdx.y, z = by >> 2, q = by & 3, bx = blockIdx.x;
  const int m0 = bx * 256, n0 = q * 256;
  const char* A = (const char*)(Xb + (size_t)m0 * 1024);
  const char* B = (const char*)(Wt + (size_t)z * 1048576 + (size_t)n0 * 1024);
  int rowl, slot; lane_src(rowl, slot);
  const size_t lo = (size_t)rowl * 2048 + slot * 16;
  f32x4 acc[8][4];
#pragma unroll
  for (int i = 0; i < 8; ++i)
#pragma unroll
    for (int c = 0; c < 4; ++c) acc[i][c] = (f32x4){0.f, 0.f, 0.f, 0.f};
  core256(A + lo, B + lo, (size_t)128 * 2048, (size_t)128 * 2048,
          OffLinear{}, OffLinear{}, 16, smem, acc);
  unsigned short* C = z == 0 ? Qm : Km;
  const int tid = threadIdx.x, w = tid >> 6, lane = tid & 63;
  const int lr = lane & 15, lq = lane >> 4;
  const int wm = (w >> 2) * 128, wn = (w & 3) * 64;
#pragma unroll
  for (int fr = 0; fr < 8; ++fr)
#pragma unroll
    for (int fc = 0; fc < 4; ++fc)
#pragma unroll
      for (int i = 0; i < 4; ++i) {
        int row = m0 + wm + fr * 16 + lq * 4 + i;
        int col = n0 + wn + fc * 16 + lr;
        C[(size_t)row * 1024 + col] = f2bf(acc[fr][fc][i]);
      }
}

// ---------- V projection: 256 blocks of 128x256 (BEFORE k_sg overlays Xb) ----------
__global__ __launch_bounds__(512, 2) void k_v(const unsigned short* __restrict__ Xb,
                                              const unsigned short* __restrict__ Wt,
                                              unsigned short* __restrict__ Vt) {
  __shared__ char smem[98304];
  const int x = blockIdx.x;
  const int m0 = (x & 7) * 128, n0 = (x >> 3) * 256;   // m over d, n over b*t
  const char* A = (const char*)(Wt + (size_t)2 * 1048576 + (size_t)m0 * 1024);
  const char* B = (const char*)(Xb + (size_t)n0 * 1024);
  int rowl, slot; lane_src(rowl, slot);
  const size_t lo = (size_t)rowl * 2048 + slot * 16;
  f32x4 acc[4][4];
#pragma unroll
  for (int a = 0; a < 4; ++a)
#pragma unroll
    for (int c = 0; c < 4; ++c) acc[a][c] = (f32x4){0.f, 0.f, 0.f, 0.f};
  core_v(A + lo, B + lo, (size_t)128 * 2048, (size_t)128 * 2048,
         OffLinear{}, OffLinear{}, 16, smem, acc);
  const int tid = threadIdx.x, w = tid >> 6, lane = tid & 63;
  const int lr = lane & 15, lq = lane >> 4;
  const int wm = (w >> 2) * 64, wn = (w & 3) * 64;
#pragma unroll
  for (int fr = 0; fr < 4; ++fr)
#pragma unroll
    for (int fc = 0; fc < 4; ++fc)
#pragma unroll
      for (int i = 0; i < 4; ++i) {
        int row = m0 + wm + fr * 16 + lq * 4 + i;   // d in [0,1024)
        int col = n0 + wn + fc * 16 + lr;           // b*t in [0,8192)
        Vt[((size_t)(col >> 11) * 1024 + row) * 2048 + (col & 2047)] = f2bf(acc[fr][fc][i]);
      }
}

// ---------- packed-tri S = scale * Q K^T ----------
__global__ __launch_bounds__(512, 2) void k_sg(const unsigned short* __restrict__ Qm,
                                               const unsigned short* __restrict__ Km,
                                               unsigned short* __restrict__ S) {
  __shared__ char smem[131072];
  const int id = blockIdx.x;   // 0..35 lower-tri tile
  int i = 0;
  while ((i + 1) * (i + 2) / 2 <= id) ++i;
  const int j = id - i * (i + 1) / 2;
  const int b = blockIdx.y;
  const int m0 = i * 256, n0 = j * 256;
  int rowl, slot; lane_src(rowl, slot);
  const size_t lo = (size_t)rowl * 2048 + slot * 16;
  f32x4 acc[8][4];
#pragma unroll
  for (int a = 0; a < 8; ++a)
#pragma unroll
    for (int c = 0; c < 4; ++c) acc[a][c] = (f32x4){0.f, 0.f, 0.f, 0.f};
  core256((const char*)(Qm + ((size_t)b * 2048 + m0) * 1024) + lo,
          (const char*)(Km + ((size_t)b * 2048 + n0) * 1024) + lo,
          (size_t)128 * 2048, (size_t)128 * 2048, OffLinear{}, OffLinear{}, 16, smem, acc);
  const float SCALE = 0.022097086912079608f;  // 1/sqrt(2048)
  const int tid = threadIdx.x, w = tid >> 6, lane = tid & 63;
  const int lr = lane & 15, lq = lane >> 4;
  const int wm = (w >> 2) * 128, wn = (w & 3) * 64;
  unsigned short* tb = S + (((size_t)(b * 36 + id)) << 16);
#pragma unroll
  for (int fr = 0; fr < 8; ++fr)
#pragma unroll
    for (int fc = 0; fc < 4; ++fc)
#pragma unroll
      for (int i2 = 0; i2 < 4; ++i2) {
        int rl = wm + fr * 16 + lq * 4 + i2;
        int cl = wn + fc * 16 + lr;
        tb[(size_t)rl * 256 + cl] = f2bf(acc[fr][fc][i2] * SCALE);
      }
}

// ---------- masked row softmax on packed S (one wave per row) ----------
__global__ __launch_bounds__(256) void k_softmax(unsigned short* __restrict__ S) {
  const int tid = threadIdx.x, w = tid >> 6, lane = tid & 63;
  const int row = blockIdx.x * 4 + w;       // 0..8191
  const int b = row >> 11, q = row & 2047;
  const int i = q >> 8, ntl = i + 1, rowL = q & 255;
  unsigned short* base = S + (((size_t)(b * 36 + (i * (i + 1)) / 2)) << 16)
                           + (size_t)rowL * 256 + lane * 4;
  float v[8][4];
#pragma unroll
  for (int t = 0; t < 8; ++t) {
    if (t < ntl) {
      ushort4 x = *(const ushort4*)(base + (size_t)t * 65536);
      int c0 = t * 256 + lane * 4;
      v[t][0] = (c0 + 0 <= q) ? bf2f(x.x) : -INFINITY;
      v[t][1] = (c0 + 1 <= q) ? bf2f(x.y) : -INFINITY;
      v[t][2] = (c0 + 2 <= q) ? bf2f(x.z) : -INFINITY;
      v[t][3] = (c0 + 3 <= q) ? bf2f(x.w) : -INFINITY;
    } else {
      v[t][0] = v[t][1] = v[t][2] = v[t][3] = -INFINITY;
    }
  }
  float m = -INFINITY;
#pragma unroll
  for (int t = 0; t < 8; ++t)
#pragma unroll
    for (int jj = 0; jj < 4; ++jj) m = fmaxf(m, v[t][jj]);
  for (int off = 32; off; off >>= 1) m = fmaxf(m, __shfl_xor(m, off));
  float s = 0.f;
#pragma unroll
  for (int t = 0; t < 8; ++t)
#pragma unroll
    for (int jj = 0; jj < 4; ++jj) { v[t][jj] = __expf(v[t][jj] - m); s += v[t][jj]; }
  for (int off = 32; off; off >>= 1) s += __shfl_xor(s, off);
  const float inv = 1.f / s;
#pragma unroll
  for (int t = 0; t < 8; ++t)
    if (t < ntl) {
      ushort4 o;
      o.x = f2bf(v[t][0] * inv); o.y = f2bf(v[t][1] * inv);
      o.z = f2bf(v[t][2] * inv); o.w = f2bf(v[t][3] * inv);
      *(ushort4*)(base + (size_t)t * 65536) = o;
    }
}

// ---------- O = P V, chunked split-K (even chunks), direct + partials ----------
__device__ const int pvi[15] = {2, 5, 5, 7, 7, 4, 4, 6, 6, 1, 3, 3, 6, 7, 0};
__device__ const int pvk[15] = {0, 0, 12, 0, 12, 0, 10, 0, 10, 0, 0, 8, 20, 24, 0};
__device__ const int pvn[15] = {12, 12, 12, 12, 12, 10, 10, 10, 10, 8, 8, 8, 8, 8, 4};
__device__ const int pvp[15] = {-1, -1, 2, -1, 5, -1, 1, -1, 3, -1, -1, 0, 4, 6, -1};

__global__ __launch_bounds__(512, 2) void k_pv(const unsigned short* __restrict__ P,
                                               const unsigned short* __restrict__ Vt,
                                               float* __restrict__ out,
                                               float* __restrict__ part) {
  __shared__ char smem[131072];
  const int cx = blockIdx.x % 15;
  const int panel = blockIdx.x / 15;        // 0..15
  const int nt = panel & 3, b = panel >> 2;
  const int i = pvi[cx], k0 = pvk[cx], nkt = pvn[cx], psl = pvp[cx];
  const char* Pb = (const char*)P + (((size_t)(b * 36 + (i * (i + 1)) / 2)) << 17);
  int rowl, slot; lane_src(rowl, slot);
  const char* Asrc = Pb + (size_t)rowl * 512 + slot * 16;
  const char* Bsrc = (const char*)Vt + ((size_t)(b * 1024 + nt * 256 + rowl)) * 4096 + slot * 16;
  f32x4 acc[8][4];
#pragma unroll
  for (int a = 0; a < 8; ++a)
#pragma unroll
    for (int c = 0; c < 4; ++c) acc[a][c] = (f32x4){0.f, 0.f, 0.f, 0.f};
  core256(Asrc, Bsrc, (size_t)128 * 512, (size_t)128 * 4096,
          OffTriK{k0}, OffLinK{k0}, nkt, smem, acc);
  const int tid = threadIdx.x, w = tid >> 6, lane = tid & 63;
  const int lr = lane & 15, lq = lane >> 4;
  const int wm = (w >> 2) * 128, wn = (w & 3) * 64;
  if (psl < 0) {
#pragma unroll
    for (int fr = 0; fr < 8; ++fr)
#pragma unroll
      for (int fc = 0; fc < 4; ++fc)
#pragma unroll
        for (int i2 = 0; i2 < 4; ++i2) {
          int orow = i * 256 + wm + fr * 16 + lq * 4 + i2;
          int col = nt * 256 + wn + fc * 16 + lr;
          out[((size_t)b * 2048 + orow) * 1024 + col] = acc[fr][fc][i2];
        }
  } else {
    float* pt = part + ((size_t)(panel * 7 + psl)) * 65536;
#pragma unroll
    for (int fr = 0; fr < 8; ++fr)
#pragma unroll
      for (int fc = 0; fc < 4; ++fc)
#pragma unroll
        for (int i2 = 0; i2 < 4; ++i2) {
          int rl = wm + fr * 16 + lq * 4 + i2;
          int cl = wn + fc * 16 + lr;
          pt[(size_t)rl * 256 + cl] = acc[fr][fc][i2];
        }
  }
}

// ---------- add split-K partials into out (rows 768..2047 of each batch) ----------
__global__ __launch_bounds__(256) void k_fix(float* __restrict__ out,
                                             const float* __restrict__ part) {
  // slots per row-tile i: 3->{0} 4->{1} 5->{2} 6->{3,4} 7->{5,6}
  const size_t e = ((size_t)blockIdx.x * 256 + threadIdx.x) * 4;  // float idx
  const int b = (int)(e / 1310720);
  const int rem = (int)(e % 1310720);
  const int row = 768 + (rem >> 10);
  const int col = rem & 1023;
  const int i = row >> 8;                    // 3..7
  const int nt = col >> 8;
  const int base4[5] = {0, 1, 2, 3, 5};
  const int cnt4[5] = {1, 1, 1, 2, 2};
  const int sb = base4[i - 3], cnt = cnt4[i - 3];
  const float* pt = part + ((size_t)((b * 4 + nt) * 7 + sb)) * 65536
                         + (size_t)(row & 255) * 256 + (col & 255);
  float* op = out + ((size_t)b * 2048 + row) * 1024 + col;
  float4 o = *(const float4*)op;
  float4 p0 = *(const float4*)pt;
  o.x += p0.x; o.y += p0.y; o.z += p0.z; o.w += p0.w;
  if (cnt == 2) {
    float4 p1 = *(const float4*)(pt + 65536);
    o.x += p1.x; o.y += p1.y; o.z += p1.z; o.w += p1.w;
  }
  *(float4*)op = o;
}

extern "C" void kernel_launch(void* const* d_in, const int* in_sizes, int n_in,
                              void* d_out, int out_size, void* d_ws, size_t ws_size,
                              hipStream_t stream) {
  const float* X  = (const float*)d_in[0];
  const float* W0p = (const float*)d_in[1];
  const float* W1p = (const float*)d_in[2];
  const float* W2p = (const float*)d_in[3];
  float* out = (float*)d_out;
  char* ws = (char*)d_ws;
  unsigned short* Xb = (unsigned short*)ws;                       // 16 MB
  unsigned short* Wt = (unsigned short*)(ws + (size_t)16777216);  // 6 MB
  unsigned short* Qm = (unsigned short*)(ws + (size_t)23068672);  // 16 MB
  unsigned short* Km = (unsigned short*)(ws + (size_t)39845888);  // 16 MB
  unsigned short* Vt = (unsigned short*)(ws + (size_t)56623104);  // 16 MB
  unsigned short* Sb = (unsigned short*)ws;                       // packed-tri S (after k_v)
  float* Pp = (float*)(ws + (size_t)23068672);                    // PV partials (dead Q/K)
  (void)in_sizes; (void)n_in; (void)out_size; (void)ws_size;

  hipLaunchKernelGGL(k_cvt, dim3(4864), dim3(256), 0, stream, X, W0p, W1p, W2p, Xb, Wt);
  hipLaunchKernelGGL(k_qk, dim3(32, 8), dim3(512), 0, stream, Xb, Wt, Qm, Km);
  hipLaunchKernelGGL(k_v, dim3(256), dim3(512), 0, stream, Xb, Wt, Vt);
  hipLaunchKernelGGL(k_sg, dim3(36, 4), dim3(512), 0, stream, Qm, Km, Sb);
  hipLaunchKernelGGL(k_softmax, dim3(2048), dim3(256), 0, stream, Sb);
  hipLaunchKernelGGL(k_pv, dim3(240), dim3(512), 0, stream, Sb, Vt, out, Pp);
  hipLaunchKernelGGL(k_fix, dim3(5120), dim3(256), 0, stream, out, Pp);
}

// Round 14
// 160.898 us; speedup vs baseline: 1.0095x; 1.0095x over previous
//
#include <hip/hip_runtime.h>
#include <cstdint>
#include <cstddef>
#include <math.h>

// CompactCausalAttention: B=4, T=2048, D_IN=D_OUT=1024, fp32 in/out.
// bf16 MFMA, 256^2 core (frozen R10 schedule). R14 = revert to best (R11).
//   ws layout (70MB):
//     Xb  bf16 [8192][1024]          @ 0        (16MB)
//     Wt  bf16 [3][1024][1024] (W^T) @ 16777216 (6MB)
//     Q   bf16 [8192][1024]          @ 23068672 (16MB)
//     K   bf16 [8192][1024]          @ 39845888 (16MB)
//     Vt  bf16 [4][1024][2048] (V^T) @ 56623104 (16MB)
//     S   bf16 [4][36][256][256] packed lower-tri @ 0 (18MB; after k_v)
//     PVpartial fp32 [112][256][256] @ 23068672 (dead Q/K)
// order: cvt -> qk -> v -> sg -> softmax -> pv -> fix

typedef __attribute__((ext_vector_type(4))) float f32x4;
typedef __attribute__((ext_vector_type(8))) short s16x8;

#define AS1(p) ((const __attribute__((address_space(1))) void*)(p))
#define AS3(p) ((__attribute__((address_space(3))) void*)(p))
#define BARRIER() asm volatile("s_barrier" ::: "memory")
#define W4 asm volatile("s_waitcnt vmcnt(4)" ::: "memory")
#define W3 asm volatile("s_waitcnt vmcnt(3)" ::: "memory")
#define W0c asm volatile("s_waitcnt vmcnt(0)" ::: "memory")
#define LGKM(n) do { asm volatile("s_waitcnt lgkmcnt(" #n ")" ::: "memory"); \
                     __builtin_amdgcn_sched_barrier(0); } while (0)
#define WNONE ((void)0)
#define NOISSUE ((void)0)

static __device__ __forceinline__ unsigned short f2bf(float x) {
  unsigned int u = __float_as_uint(x);
  unsigned int r = u + 0x7FFFu + ((u >> 16) & 1u);   // RNE
  return (unsigned short)(r >> 16);
}
static __device__ __forceinline__ float bf2f(unsigned short h) {
  return __uint_as_float(((unsigned int)h) << 16);
}

// ---------- merged convert: X (blocks 0..4095) + W transpose (4096..4863) ----------
__global__ __launch_bounds__(256) void k_cvt(const float* __restrict__ X,
                                             const float* __restrict__ W0p,
                                             const float* __restrict__ W1p,
                                             const float* __restrict__ W2p,
                                             unsigned short* __restrict__ Xb,
                                             unsigned short* __restrict__ Wt) {
  __shared__ float tile[64][65];
  const int bx = blockIdx.x;
  if (bx < 4096) {
    size_t i = ((size_t)bx * 256 + threadIdx.x) * 8;
    float4 a = *(const float4*)(X + i);
    float4 b = *(const float4*)(X + i + 4);
    union { unsigned short us[8]; uint4 v; } o;
    o.us[0] = f2bf(a.x); o.us[1] = f2bf(a.y); o.us[2] = f2bf(a.z); o.us[3] = f2bf(a.w);
    o.us[4] = f2bf(b.x); o.us[5] = f2bf(b.y); o.us[6] = f2bf(b.z); o.us[7] = f2bf(b.w);
    *(uint4*)(Xb + i) = o.v;
    return;
  }
  const int bx2 = bx - 4096;
  const int z = bx2 >> 8, t = bx2 & 255;
  const float* W = z == 0 ? W0p : (z == 1 ? W1p : W2p);
  unsigned short* dst = Wt + (size_t)z * 1048576;
  const int k0 = (t >> 4) * 64, n0 = (t & 15) * 64;
  const int tr = threadIdx.x >> 4, tc = (threadIdx.x & 15) * 4;
  for (int i = 0; i < 4; ++i) {
    int r = tr + i * 16;
    float4 v = *(const float4*)(W + (size_t)(k0 + r) * 1024 + n0 + tc);
    tile[r][tc + 0] = v.x; tile[r][tc + 1] = v.y;
    tile[r][tc + 2] = v.z; tile[r][tc + 3] = v.w;
  }
  __syncthreads();
  for (int i = 0; i < 4; ++i) {
    int r = tr + i * 16;  // n-local
    ushort4 o;
    o.x = f2bf(tile[tc + 0][r]); o.y = f2bf(tile[tc + 1][r]);
    o.z = f2bf(tile[tc + 2][r]); o.w = f2bf(tile[tc + 3][r]);
    *(ushort4*)(dst + (size_t)(n0 + r) * 1024 + k0 + tc) = o;
  }
}

// ====================== 256^2 core (frozen R10) ======================
static __device__ __forceinline__ void stage2(const char* src, size_t ld128, char* dst) {
  __builtin_amdgcn_global_load_lds(AS1(src), AS3(dst), 16, 0, 0);
  __builtin_amdgcn_global_load_lds(AS1(src + ld128), AS3(dst + 8192), 16, 0, 0);
}

template <class FA, class FB>
static __device__ __forceinline__ void core256(const char* __restrict__ As,
                                               const char* __restrict__ Bs,
                                               size_t ldA128, size_t ldB128,
                                               FA offA, FB offB,
                                               int nkt, char* smem, f32x4 (&acc)[8][4]) {
  const int tid = threadIdx.x, w = tid >> 6, lane = tid & 63;
  const int lr = lane & 15, lq = lane >> 4;
  const int wm = (w >> 2) * 128, wn = (w & 3) * 64;
  char* ldsA = smem + w * 1024;
  char* ldsB = smem + 65536 + w * 1024;
  s16x8 afA[4], afB[4], bfr[4];

#define STG_A(t, h) stage2(As + offA((t), (h)), ldA128, ldsA + (((t) & 1) * 2 + (h)) * 16384)
#define STG_B(t, h) stage2(Bs + offB((t), (h)), ldB128, ldsB + (((t) & 1) * 2 + (h)) * 16384)
#define STG(t, h) do { STG_A(t, h); STG_B(t, h); } while (0)
#define RD_A(buf, h, r) (*(const s16x8*)(smem + ((buf) * 2 + (h)) * 16384 + (r) * 64 + ((lq ^ (((r) >> 1) & 3)) << 4)))
#define RD_B(buf, h, r) (*(const s16x8*)(smem + 65536 + ((buf) * 2 + (h)) * 16384 + (r) * 64 + ((lq ^ (((r) >> 1) & 3)) << 4)))
#define MMQ(AF, BF, base) \
  _Pragma("unroll") for (int i = 0; i < 4; ++i) \
  _Pragma("unroll") for (int c = 0; c < 4; ++c) \
    acc[(base) + i][c] = __builtin_amdgcn_mfma_f32_16x16x32_bf16(AF[i], BF[c], acc[(base) + i][c], 0, 0, 0)
#define PHASE(TT, HH, ISSUE, WVM) { \
    const int _bf = (TT) & 1; \
    _Pragma("unroll") for (int i = 0; i < 4; ++i) afA[i] = RD_A(_bf, HH, wm + i * 16 + lr); \
    _Pragma("unroll") for (int c = 0; c < 4; ++c) bfr[c] = RD_B(_bf, HH, wn + c * 16 + lr); \
    _Pragma("unroll") for (int i = 0; i < 4; ++i) afB[i] = RD_A(_bf, HH, wm + 64 + i * 16 + lr); \
    ISSUE; WVM; BARRIER(); \
    LGKM(4); \
    __builtin_amdgcn_s_setprio(1); \
    MMQ(afA, bfr, 0); \
    LGKM(0); \
    MMQ(afB, bfr, 4); \
    __builtin_amdgcn_s_setprio(0); \
  }

  STG(0, 0); STG(0, 1);
  W4; BARRIER();

  int t = 0;
  for (; t + 1 < nkt; ++t) {
    PHASE(t, 0, STG(t + 1, 0), W4)
    PHASE(t, 1, STG(t + 1, 1), W4)
  }
  PHASE(t, 0, NOISSUE, W0c)
  PHASE(t, 1, NOISSUE, WNONE)

#undef STG_A
#undef STG_B
#undef STG
#undef RD_A
#undef RD_B
#undef MMQ
#undef PHASE
}

// ====================== 128x256 core (k_v) ======================
// 8 waves, wave tile 64x64 (wm=(w>>2)*64, wn=(w&3)*64). LDS 96KB:
// A [2buf][2h][128][32] @ 0 (32KB), B [2buf][2h][256][32] @ 32768 (64KB).
// Per phase: 8 ds_read, 3 staging loads, vmcnt(3), barrier, lgkm(0), 16 MFMA.
template <class FA, class FB>
static __device__ __forceinline__ void core_v(const char* __restrict__ As,
                                              const char* __restrict__ Bs,
                                              size_t ldA128, size_t ldB128,
                                              FA offA, FB offB,
                                              int nkt, char* smem, f32x4 (&acc)[4][4]) {
  const int tid = threadIdx.x, w = tid >> 6, lane = tid & 63;
  const int lr = lane & 15, lq = lane >> 4;
  const int wm = (w >> 2) * 64, wn = (w & 3) * 64;
  char* ldsA = smem + w * 1024;
  char* ldsB = smem + 32768 + w * 1024;
  s16x8 af[4], bfr[4];

#define STG_A(t, h) __builtin_amdgcn_global_load_lds(AS1(As + offA((t), (h))), \
    AS3(ldsA + (((t) & 1) * 2 + (h)) * 8192), 16, 0, 0)
#define STG_B(t, h) stage2(Bs + offB((t), (h)), ldB128, ldsB + (((t) & 1) * 2 + (h)) * 16384)
#define STG(t, h) do { STG_A(t, h); STG_B(t, h); } while (0)
#define RD_A(buf, h, r) (*(const s16x8*)(smem + ((buf) * 2 + (h)) * 8192 + (r) * 64 + ((lq ^ (((r) >> 1) & 3)) << 4)))
#define RD_B(buf, h, r) (*(const s16x8*)(smem + 32768 + ((buf) * 2 + (h)) * 16384 + (r) * 64 + ((lq ^ (((r) >> 1) & 3)) << 4)))
#define PHASE(TT, HH, ISSUE, WVM) { \
    const int _bf = (TT) & 1; \
    _Pragma("unroll") for (int i = 0; i < 4; ++i) af[i] = RD_A(_bf, HH, wm + i * 16 + lr); \
    _Pragma("unroll") for (int c = 0; c < 4; ++c) bfr[c] = RD_B(_bf, HH, wn + c * 16 + lr); \
    ISSUE; WVM; BARRIER(); \
    LGKM(0); \
    __builtin_amdgcn_s_setprio(1); \
    _Pragma("unroll") for (int i = 0; i < 4; ++i) \
    _Pragma("unroll") for (int c = 0; c < 4; ++c) \
      acc[i][c] = __builtin_amdgcn_mfma_f32_16x16x32_bf16(af[i], bfr[c], acc[i][c], 0, 0, 0); \
    __builtin_amdgcn_s_setprio(0); \
  }

  STG(0, 0); STG(0, 1);   // 6 loads in flight
  W3; BARRIER();          // seal (0,h0)

  int t = 0;
  for (; t + 1 < nkt; ++t) {
    PHASE(t, 0, STG(t + 1, 0), W3)   // seals (t,h1)
    PHASE(t, 1, STG(t + 1, 1), W3)   // seals (t+1,h0)
  }
  PHASE(t, 0, NOISSUE, W0c)          // seals (t,h1)
  PHASE(t, 1, NOISSUE, WNONE)

#undef STG_A
#undef STG_B
#undef STG
#undef RD_A
#undef RD_B
#undef PHASE
}

struct OffLinear {
  __device__ __forceinline__ size_t operator()(int t, int h) const {
    return (size_t)t * 128 + (size_t)h * 64;
  }
};
struct OffTriK {   // packed S tiles with k-chunk offset (BK64 units)
  int k0;
  __device__ __forceinline__ size_t operator()(int t, int h) const {
    int g = k0 + t;
    return (size_t)(g >> 2) * 131072 + (size_t)(g & 3) * 128 + (size_t)h * 64;
  }
};
struct OffLinK {   // linear with k-chunk offset
  int k0;
  __device__ __forceinline__ size_t operator()(int t, int h) const {
    return (size_t)(k0 + t) * 128 + (size_t)h * 64;
  }
};

static __device__ __forceinline__ void lane_src(int& rowl, int& slot) {
  const int tid = threadIdx.x, w = tid >> 6, lane = tid & 63;
  rowl = w * 16 + (lane >> 2);
  slot = (lane & 3) ^ ((rowl >> 1) & 3);
}

// ---------- Q,K projection: 256 blocks ----------
__global__ __launch_bounds__(512, 2) void k_qk(const unsigned short* __restrict__ Xb,
                                               const unsigned short* __restrict__ Wt,
                                               unsigned short* __restrict__ Qm,
                                               unsigned short* __restrict__ Km) {
  __shared__ char smem[131072];
  const int by = blockIdx.y, z = by >> 2, q = by & 3, bx = blockIdx.x;
  const int m0 = bx * 256, n0 = q * 256;
  const char* A = (const char*)(Xb + (size_t)m0 * 1024);
  const char* B = (const char*)(Wt + (size_t)z * 1048576 + (size_t)n0 * 1024);
  int rowl, slot; lane_src(rowl, slot);
  const size_t lo = (size_t)rowl * 2048 + slot * 16;
  f32x4 acc[8][4];
#pragma unroll
  for (int i = 0; i < 8; ++i)
#pragma unroll
    for (int c = 0; c < 4; ++c) acc[i][c] = (f32x4){0.f, 0.f, 0.f, 0.f};
  core256(A + lo, B + lo, (size_t)128 * 2048, (size_t)128 * 2048,
          OffLinear{}, OffLinear{}, 16, smem, acc);
  unsigned short* C = z == 0 ? Qm : Km;
  const int tid = threadIdx.x, w = tid >> 6, lane = tid & 63;
  const int lr = lane & 15, lq = lane >> 4;
  const int wm = (w >> 2) * 128, wn = (w & 3) * 64;
#pragma unroll
  for (int fr = 0; fr < 8; ++fr)
#pragma unroll
    for (int fc = 0; fc < 4; ++fc)
#pragma unroll
      for (int i = 0; i < 4; ++i) {
        int row = m0 + wm + fr * 16 + lq * 4 + i;
        int col = n0 + wn + fc * 16 + lr;
        C[(size_t)row * 1024 + col] = f2bf(acc[fr][fc][i]);
      }
}

// ---------- V projection: 256 blocks of 128x256 (BEFORE k_sg overlays Xb) ----------
__global__ __launch_bounds__(512, 2) void k_v(const unsigned short* __restrict__ Xb,
                                              const unsigned short* __restrict__ Wt,
                                              unsigned short* __restrict__ Vt) {
  __shared__ char smem[98304];
  const int x = blockIdx.x;
  const int m0 = (x & 7) * 128, n0 = (x >> 3) * 256;   // m over d, n over b*t
  const char* A = (const char*)(Wt + (size_t)2 * 1048576 + (size_t)m0 * 1024);
  const char* B = (const char*)(Xb + (size_t)n0 * 1024);
  int rowl, slot; lane_src(rowl, slot);
  const size_t lo = (size_t)rowl * 2048 + slot * 16;
  f32x4 acc[4][4];
#pragma unroll
  for (int a = 0; a < 4; ++a)
#pragma unroll
    for (int c = 0; c < 4; ++c) acc[a][c] = (f32x4){0.f, 0.f, 0.f, 0.f};
  core_v(A + lo, B + lo, (size_t)128 * 2048, (size_t)128 * 2048,
         OffLinear{}, OffLinear{}, 16, smem, acc);
  const int tid = threadIdx.x, w = tid >> 6, lane = tid & 63;
  const int lr = lane & 15, lq = lane >> 4;
  const int wm = (w >> 2) * 64, wn = (w & 3) * 64;
#pragma unroll
  for (int fr = 0; fr < 4; ++fr)
#pragma unroll
    for (int fc = 0; fc < 4; ++fc)
#pragma unroll
      for (int i = 0; i < 4; ++i) {
        int row = m0 + wm + fr * 16 + lq * 4 + i;   // d in [0,1024)
        int col = n0 + wn + fc * 16 + lr;           // b*t in [0,8192)
        Vt[((size_t)(col >> 11) * 1024 + row) * 2048 + (col & 2047)] = f2bf(acc[fr][fc][i]);
      }
}

// ---------- packed-tri S = scale * Q K^T ----------
__global__ __launch_bounds__(512, 2) void k_sg(const unsigned short* __restrict__ Qm,
                                               const unsigned short* __restrict__ Km,
                                               unsigned short* __restrict__ S) {
  __shared__ char smem[131072];
  const int id = blockIdx.x;   // 0..35 lower-tri tile
  int i = 0;
  while ((i + 1) * (i + 2) / 2 <= id) ++i;
  const int j = id - i * (i + 1) / 2;
  const int b = blockIdx.y;
  const int m0 = i * 256, n0 = j * 256;
  int rowl, slot; lane_src(rowl, slot);
  const size_t lo = (size_t)rowl * 2048 + slot * 16;
  f32x4 acc[8][4];
#pragma unroll
  for (int a = 0; a < 8; ++a)
#pragma unroll
    for (int c = 0; c < 4; ++c) acc[a][c] = (f32x4){0.f, 0.f, 0.f, 0.f};
  core256((const char*)(Qm + ((size_t)b * 2048 + m0) * 1024) + lo,
          (const char*)(Km + ((size_t)b * 2048 + n0) * 1024) + lo,
          (size_t)128 * 2048, (size_t)128 * 2048, OffLinear{}, OffLinear{}, 16, smem, acc);
  const float SCALE = 0.022097086912079608f;  // 1/sqrt(2048)
  const int tid = threadIdx.x, w = tid >> 6, lane = tid & 63;
  const int lr = lane & 15, lq = lane >> 4;
  const int wm = (w >> 2) * 128, wn = (w & 3) * 64;
  unsigned short* tb = S + (((size_t)(b * 36 + id)) << 16);
#pragma unroll
  for (int fr = 0; fr < 8; ++fr)
#pragma unroll
    for (int fc = 0; fc < 4; ++fc)
#pragma unroll
      for (int i2 = 0; i2 < 4; ++i2) {
        int rl = wm + fr * 16 + lq * 4 + i2;
        int cl = wn + fc * 16 + lr;
        tb[(size_t)rl * 256 + cl] = f2bf(acc[fr][fc][i2] * SCALE);
      }
}

// ---------- masked row softmax on packed S (one wave per row) ----------
__global__ __launch_bounds__(256) void k_softmax(unsigned short* __restrict__ S) {
  const int tid = threadIdx.x, w = tid >> 6, lane = tid & 63;
  const int row = blockIdx.x * 4 + w;       // 0..8191
  const int b = row >> 11, q = row & 2047;
  const int i = q >> 8, ntl = i + 1, rowL = q & 255;
  unsigned short* base = S + (((size_t)(b * 36 + (i * (i + 1)) / 2)) << 16)
                           + (size_t)rowL * 256 + lane * 4;
  float v[8][4];
#pragma unroll
  for (int t = 0; t < 8; ++t) {
    if (t < ntl) {
      ushort4 x = *(const ushort4*)(base + (size_t)t * 65536);
      int c0 = t * 256 + lane * 4;
      v[t][0] = (c0 + 0 <= q) ? bf2f(x.x) : -INFINITY;
      v[t][1] = (c0 + 1 <= q) ? bf2f(x.y) : -INFINITY;
      v[t][2] = (c0 + 2 <= q) ? bf2f(x.z) : -INFINITY;
      v[t][3] = (c0 + 3 <= q) ? bf2f(x.w) : -INFINITY;
    } else {
      v[t][0] = v[t][1] = v[t][2] = v[t][3] = -INFINITY;
    }
  }
  float m = -INFINITY;
#pragma unroll
  for (int t = 0; t < 8; ++t)
#pragma unroll
    for (int jj = 0; jj < 4; ++jj) m = fmaxf(m, v[t][jj]);
  for (int off = 32; off; off >>= 1) m = fmaxf(m, __shfl_xor(m, off));
  float s = 0.f;
#pragma unroll
  for (int t = 0; t < 8; ++t)
#pragma unroll
    for (int jj = 0; jj < 4; ++jj) { v[t][jj] = __expf(v[t][jj] - m); s += v[t][jj]; }
  for (int off = 32; off; off >>= 1) s += __shfl_xor(s, off);
  const float inv = 1.f / s;
#pragma unroll
  for (int t = 0; t < 8; ++t)
    if (t < ntl) {
      ushort4 o;
      o.x = f2bf(v[t][0] * inv); o.y = f2bf(v[t][1] * inv);
      o.z = f2bf(v[t][2] * inv); o.w = f2bf(v[t][3] * inv);
      *(ushort4*)(base + (size_t)t * 65536) = o;
    }
}

// ---------- O = P V, chunked split-K (even chunks), direct + partials ----------
__device__ const int pvi[15] = {2, 5, 5, 7, 7, 4, 4, 6, 6, 1, 3, 3, 6, 7, 0};
__device__ const int pvk[15] = {0, 0, 12, 0, 12, 0, 10, 0, 10, 0, 0, 8, 20, 24, 0};
__device__ const int pvn[15] = {12, 12, 12, 12, 12, 10, 10, 10, 10, 8, 8, 8, 8, 8, 4};
__device__ const int pvp[15] = {-1, -1, 2, -1, 5, -1, 1, -1, 3, -1, -1, 0, 4, 6, -1};

__global__ __launch_bounds__(512, 2) void k_pv(const unsigned short* __restrict__ P,
                                               const unsigned short* __restrict__ Vt,
                                               float* __restrict__ out,
                                               float* __restrict__ part) {
  __shared__ char smem[131072];
  const int cx = blockIdx.x % 15;
  const int panel = blockIdx.x / 15;        // 0..15
  const int nt = panel & 3, b = panel >> 2;
  const int i = pvi[cx], k0 = pvk[cx], nkt = pvn[cx], psl = pvp[cx];
  const char* Pb = (const char*)P + (((size_t)(b * 36 + (i * (i + 1)) / 2)) << 17);
  int rowl, slot; lane_src(rowl, slot);
  const char* Asrc = Pb + (size_t)rowl * 512 + slot * 16;
  const char* Bsrc = (const char*)Vt + ((size_t)(b * 1024 + nt * 256 + rowl)) * 4096 + slot * 16;
  f32x4 acc[8][4];
#pragma unroll
  for (int a = 0; a < 8; ++a)
#pragma unroll
    for (int c = 0; c < 4; ++c) acc[a][c] = (f32x4){0.f, 0.f, 0.f, 0.f};
  core256(Asrc, Bsrc, (size_t)128 * 512, (size_t)128 * 4096,
          OffTriK{k0}, OffLinK{k0}, nkt, smem, acc);
  const int tid = threadIdx.x, w = tid >> 6, lane = tid & 63;
  const int lr = lane & 15, lq = lane >> 4;
  const int wm = (w >> 2) * 128, wn = (w & 3) * 64;
  if (psl < 0) {
#pragma unroll
    for (int fr = 0; fr < 8; ++fr)
#pragma unroll
      for (int fc = 0; fc < 4; ++fc)
#pragma unroll
        for (int i2 = 0; i2 < 4; ++i2) {
          int orow = i * 256 + wm + fr * 16 + lq * 4 + i2;
          int col = nt * 256 + wn + fc * 16 + lr;
          out[((size_t)b * 2048 + orow) * 1024 + col] = acc[fr][fc][i2];
        }
  } else {
    float* pt = part + ((size_t)(panel * 7 + psl)) * 65536;
#pragma unroll
    for (int fr = 0; fr < 8; ++fr)
#pragma unroll
      for (int fc = 0; fc < 4; ++fc)
#pragma unroll
        for (int i2 = 0; i2 < 4; ++i2) {
          int rl = wm + fr * 16 + lq * 4 + i2;
          int cl = wn + fc * 16 + lr;
          pt[(size_t)rl * 256 + cl] = acc[fr][fc][i2];
        }
  }
}

// ---------- add split-K partials into out (rows 768..2047 of each batch) ----------
__global__ __launch_bounds__(256) void k_fix(float* __restrict__ out,
                                             const float* __restrict__ part) {
  // slots per row-tile i: 3->{0} 4->{1} 5->{2} 6->{3,4} 7->{5,6}
  const size_t e = ((size_t)blockIdx.x * 256 + threadIdx.x) * 4;  // float idx
  const int b = (int)(e / 1310720);
  const int rem = (int)(e % 1310720);
  const int row = 768 + (rem >> 10);
  const int col = rem & 1023;
  const int i = row >> 8;                    // 3..7
  const int nt = col >> 8;
  const int base4[5] = {0, 1, 2, 3, 5};
  const int cnt4[5] = {1, 1, 1, 2, 2};
  const int sb = base4[i - 3], cnt = cnt4[i - 3];
  const float* pt = part + ((size_t)((b * 4 + nt) * 7 + sb)) * 65536
                         + (size_t)(row & 255) * 256 + (col & 255);
  float* op = out + ((size_t)b * 2048 + row) * 1024 + col;
  float4 o = *(const float4*)op;
  float4 p0 = *(const float4*)pt;
  o.x += p0.x; o.y += p0.y; o.z += p0.z; o.w += p0.w;
  if (cnt == 2) {
    float4 p1 = *(const float4*)(pt + 65536);
    o.x += p1.x; o.y += p1.y; o.z += p1.z; o.w += p1.w;
  }
  *(float4*)op = o;
}

extern "C" void kernel_launch(void* const* d_in, const int* in_sizes, int n_in,
                              void* d_out, int out_size, void* d_ws, size_t ws_size,
                              hipStream_t stream) {
  const float* X  = (const float*)d_in[0];
  const float* W0p = (const float*)d_in[1];
  const float* W1p = (const float*)d_in[2];
  const float* W2p = (const float*)d_in[3];
  float* out = (float*)d_out;
  char* ws = (char*)d_ws;
  unsigned short* Xb = (unsigned short*)ws;                       // 16 MB
  unsigned short* Wt = (unsigned short*)(ws + (size_t)16777216);  // 6 MB
  unsigned short* Qm = (unsigned short*)(ws + (size_t)23068672);  // 16 MB
  unsigned short* Km = (unsigned short*)(ws + (size_t)39845888);  // 16 MB
  unsigned short* Vt = (unsigned short*)(ws + (size_t)56623104);  // 16 MB
  unsigned short* Sb = (unsigned short*)ws;                       // packed-tri S (after k_v)
  float* Pp = (float*)(ws + (size_t)23068672);                    // PV partials (dead Q/K)
  (void)in_sizes; (void)n_in; (void)out_size; (void)ws_size;

  hipLaunchKernelGGL(k_cvt, dim3(4864), dim3(256), 0, stream, X, W0p, W1p, W2p, Xb, Wt);
  hipLaunchKernelGGL(k_qk, dim3(32, 8), dim3(512), 0, stream, Xb, Wt, Qm, Km);
  hipLaunchKernelGGL(k_v, dim3(256), dim3(512), 0, stream, Xb, Wt, Vt);
  hipLaunchKernelGGL(k_sg, dim3(36, 4), dim3(512), 0, stream, Qm, Km, Sb);
  hipLaunchKernelGGL(k_softmax, dim3(2048), dim3(256), 0, stream, Sb);
  hipLaunchKernelGGL(k_pv, dim3(240), dim3(512), 0, stream, Sb, Vt, out, Pp);
  hipLaunchKernelGGL(k_fix, dim3(5120), dim3(256), 0, stream, out, Pp);
}